// Round 8
// baseline (51.993 us; speedup 1.0000x reference)
//
#include <hip/hip_runtime.h>
#include <hip/hip_bf16.h>
#include <math.h>

// image: (B=32, D=64, H=64, W=128) f32
// polar_log_depths: (B=32, H=64, W=128, S=64) f32
// outputs: image_polar (B,D,Z=64,W) f32, cell_score (B,W,Z) f32, concat flat.
#define B_ 32
#define D_ 64
#define H_ 64
#define W_ 128
#define S_ 64
#define Z_ 64
#define WT 4

typedef __attribute__((ext_vector_type(8))) short bf16x8;
typedef __attribute__((ext_vector_type(4))) float f32x4;

static __device__ __forceinline__ short f2bf(float f) {
    union { __hip_bfloat16 h; short s; } u;
    u.h = __float2bfloat16(f);
    return u.s;
}
static __device__ __forceinline__ float getc(const float4& v, int k) {
    switch (k) { case 0: return v.x; case 1: return v.y; case 2: return v.z; default: return v.w; }
}

// Swizzled byte offset of a 16B column-octet slot in an 8KB [64][128B] plane.
static __device__ __forceinline__ int swz(int w, int row, int oct) {
    return w * 8192 + row * 128 + (((oct ^ row ^ w) & 7) << 4);
}

__global__ __launch_bounds__(512, 4)
void polar_proj_kernel(const float* __restrict__ image,
                       const float* __restrict__ polar,
                       float* __restrict__ out_img,
                       float* __restrict__ out_cell) {
    __shared__ __align__(16) unsigned char sP[WT * 8192];  // polar bf16 [w][h][s] -> prob^T [w][z][h]
    __shared__ __align__(16) unsigned char sA[WT * 8192];  // image bf16 [w][d][h]

    const int t = threadIdx.x;

    // XCD-bijective swizzle: grid 1024 (%8==0); 128 consecutive logical ids
    // (same/adjacent w-tiles sharing image & output lines) per XCD.
    const int cpx = gridDim.x >> 3;
    const int logical = (blockIdx.x & 7) * cpx + (blockIdx.x >> 3);
    const int b  = logical >> 5;
    const int w0 = (logical & 31) << 2;

    // ---- 1. image loads: thread owns (d, h-quad) = 64B contiguous. ----
    float4 ir[2][4];
#pragma unroll
    for (int i = 0; i < 2; ++i) {
        const int g  = i * 512 + t;
        const int d  = g >> 4;
        const int h0 = (g & 15) << 2;
#pragma unroll
        for (int k = 0; k < 4; ++k)
            ir[i][k] = *(const float4*)(image + ((size_t)((b * D_ + d) * H_ + h0 + k)) * W_ + w0);
    }

    // ---- 2. polar loads: 4 lanes x 16B interleaved per 256B row. ----
    const int q4 = t & 3;
    const int rbase = t >> 2;                 // 0..127
    float4 pr[2][4];
#pragma unroll
    for (int rp = 0; rp < 2; ++rp) {
        const int rr = rp * 128 + rbase;      // rr = w*64 + h
        const int w = rr >> 6, h = rr & 63;
        const float* src = polar + ((size_t)((b * H_ + h) * W_ + w0 + w)) * S_ + q4 * 16;
#pragma unroll
        for (int k = 0; k < 4; ++k)
            pr[rp][k] = *(const float4*)(src + k * 4);
    }

    // ---- 3. image -> sA (bf16, b64 h-quad packs, swizzled, bank floor). ----
#pragma unroll
    for (int i = 0; i < 2; ++i) {
        const int g  = i * 512 + t;
        const int d  = g >> 4;
        const int h0 = (g & 15) << 2;
#pragma unroll
        for (int w = 0; w < 4; ++w) {
            const short s0 = f2bf(getc(ir[i][0], w));
            const short s1 = f2bf(getc(ir[i][1], w));
            const short s2 = f2bf(getc(ir[i][2], w));
            const short s3 = f2bf(getc(ir[i][3], w));
            int2 pk;
            pk.x = (s0 & 0xffff) | (s1 << 16);
            pk.y = (s2 & 0xffff) | (s3 << 16);
            *(int2*)(sA + swz(w, d, h0 >> 3) + ((h0 & 7) << 1)) = pk;
        }
    }

    // ---- 4. polar -> sP (bf16x8 b128, swizzled). ----
#pragma unroll
    for (int rp = 0; rp < 2; ++rp) {
        const int rr = rp * 128 + rbase;
        const int w = rr >> 6, h = rr & 63;
#pragma unroll
        for (int c = 0; c < 2; ++c) {
            bf16x8 v;
#pragma unroll
            for (int e = 0; e < 8; ++e)
                v[e] = f2bf(getc(pr[rp][c * 2 + (e >> 2)], e & 3));
            *(bf16x8*)(sP + swz(w, h, q4 * 2 + c)) = v;
        }
    }
    __syncthreads();   // staging ready

    // ---- 5. interp as MFMA with register-built Wz. wave = (wS, zh). ----
    const int lane = t & 63;
    const int wv   = t >> 6;
    const int fr   = lane & 15, lg = lane >> 4;
    const int wS   = wv >> 1, zh = wv & 1;

    int   i0_[2];
    float wz_[2];
#pragma unroll
    for (int nt = 0; nt < 2; ++nt) {
        const int z = zh * 32 + nt * 16 + fr;
        const float posf = (log2f(0.5f + 0.5f * (float)z) + 1.0f) * 10.5f;  // (63/6)
        int i0 = (int)floorf(posf);
        i0 = i0 < 0 ? 0 : (i0 > S_ - 1 ? S_ - 1 : i0);
        i0_[nt] = i0;
        wz_[nt] = posf - (float)i0;
    }
    bf16x8 bw[2][2];   // [ks][nt]: Wz^T fragment, 2 nonzeros per z-column
#pragma unroll
    for (int ks = 0; ks < 2; ++ks)
#pragma unroll
        for (int nt = 0; nt < 2; ++nt) {
            const int i0 = i0_[nt];
            const int i1 = (i0 + 1 > S_ - 1) ? (S_ - 1) : (i0 + 1);
            const float wz = wz_[nt];
#pragma unroll
            for (int e = 0; e < 8; ++e) {
                const int s = ks * 32 + lg * 8 + e;
                const float v = (s == i0 ? 1.0f - wz : 0.0f) + (s == i1 ? wz : 0.0f);
                bw[ks][nt][e] = f2bf(v);
            }
        }

    f32x4 sacc[4][2] = {};
#pragma unroll
    for (int ks = 0; ks < 2; ++ks)
#pragma unroll
        for (int mt = 0; mt < 4; ++mt) {
            const bf16x8 a = *(const bf16x8*)(sP + swz(wS, mt * 16 + fr, ks * 4 + lg));
            sacc[mt][0] = __builtin_amdgcn_mfma_f32_16x16x32_bf16(a, bw[ks][0], sacc[mt][0], 0, 0, 0);
            sacc[mt][1] = __builtin_amdgcn_mfma_f32_16x16x32_bf16(a, bw[ks][1], sacc[mt][1], 0, 0, 0);
        }

    // ---- softmax over h, in-register, no max-subtract (|score| <~ 6). ----
    float ex[4][2][4];
    float ss0 = 0.0f, ss1 = 0.0f;
#pragma unroll
    for (int mt = 0; mt < 4; ++mt)
#pragma unroll
        for (int r = 0; r < 4; ++r) {
            const float e0 = __expf(sacc[mt][0][r]);
            const float e1 = __expf(sacc[mt][1][r]);
            ex[mt][0][r] = e0;
            ex[mt][1][r] = e1;
            ss0 += e0;
            ss1 += e1;
        }
    ss0 += __shfl_xor(ss0, 16);
    ss0 += __shfl_xor(ss0, 32);
    ss1 += __shfl_xor(ss1, 16);
    ss1 += __shfl_xor(ss1, 32);
    if (lg == 0) {
        float* oc = out_cell + ((size_t)b * W_ + w0 + wS) * Z_ + zh * 32 + fr;
        oc[0]  = __logf(ss0);
        oc[16] = __logf(ss1);
    }
    const float inv0 = 1.0f / ss0;
    const float inv1 = 1.0f / ss1;
    __syncthreads();   // all S-GEMM reads of sP done; safe to overwrite

    // ---- 6. prob^T -> sP rows z (b64 packs of 4 h-contiguous bf16). ----
#pragma unroll
    for (int nt = 0; nt < 2; ++nt) {
        const int zrow = zh * 32 + nt * 16 + fr;
        const float inv = nt ? inv1 : inv0;
#pragma unroll
        for (int mt = 0; mt < 4; ++mt) {
            const short p0 = f2bf(ex[mt][nt][0] * inv);
            const short p1 = f2bf(ex[mt][nt][1] * inv);
            const short p2 = f2bf(ex[mt][nt][2] * inv);
            const short p3 = f2bf(ex[mt][nt][3] * inv);
            int2 pk;
            pk.x = (p0 & 0xffff) | (p1 << 16);
            pk.y = (p2 & 0xffff) | (p3 << 16);
            *(int2*)(sP + swz(wS, zrow, mt * 2 + (lg >> 1)) + ((lg & 1) << 3)) = pk;
        }
    }
    __syncthreads();   // operands ready

    // ---- 7. PV GEMM: wave (mtp,ntp) does 16d x 32z x 4w, K=64. ----
    const int mtp = wv >> 1, ntp = wv & 1;
    const int rowA = mtp * 16 + fr;
    f32x4 acc[4][2] = {};   // [w][zz]
#pragma unroll
    for (int w = 0; w < 4; ++w)
#pragma unroll
        for (int ks = 0; ks < 2; ++ks) {
            const bf16x8 a = *(const bf16x8*)(sA + swz(w, rowA, ks * 4 + lg));
#pragma unroll
            for (int zz = 0; zz < 2; ++zz) {
                const bf16x8 bb = *(const bf16x8*)(sP + swz(w, ntp * 32 + zz * 16 + fr, ks * 4 + lg));
                acc[w][zz] = __builtin_amdgcn_mfma_f32_16x16x32_bf16(a, bb, acc[w][zz], 0, 0, 0);
            }
        }

    // ---- 8. direct stores: one float4 over w per (d,z). ----
#pragma unroll
    for (int zz = 0; zz < 2; ++zz)
#pragma unroll
        for (int r = 0; r < 4; ++r) {
            const int d = mtp * 16 + lg * 4 + r;
            const int z = ntp * 32 + zz * 16 + fr;
            float4 o;
            o.x = acc[0][zz][r];
            o.y = acc[1][zz][r];
            o.z = acc[2][zz][r];
            o.w = acc[3][zz][r];
            *(float4*)(out_img + ((size_t)((b * D_ + d) * Z_) + z) * W_ + w0) = o;
        }
}

extern "C" void kernel_launch(void* const* d_in, const int* in_sizes, int n_in,
                              void* d_out, int out_size, void* d_ws, size_t ws_size,
                              hipStream_t stream) {
    const float* image = (const float*)d_in[0];
    const float* polar = (const float*)d_in[1];
    float* out_img  = (float*)d_out;
    float* out_cell = out_img + (size_t)B_ * D_ * Z_ * W_;
    dim3 grid(B_ * (W_ / WT));   // 1024 blocks
    polar_proj_kernel<<<grid, 512, 0, stream>>>(image, polar, out_img, out_cell);
}

// Round 9
// 51.112 us; speedup vs baseline: 1.0172x; 1.0172x over previous
//
#include <hip/hip_runtime.h>
#include <hip/hip_bf16.h>
#include <math.h>

// image: (B=32, D=64, H=64, W=128) f32
// polar_log_depths: (B=32, H=64, W=128, S=64) f32
// outputs: image_polar (B,D,Z=64,W) f32, cell_score (B,W,Z) f32, concat flat.
#define B_ 32
#define D_ 64
#define H_ 64
#define W_ 128
#define S_ 64
#define Z_ 64
#define WT 4

typedef __attribute__((ext_vector_type(8))) short bf16x8;
typedef __attribute__((ext_vector_type(4))) float f32x4;

static __device__ __forceinline__ short f2bf(float f) {
    union { __hip_bfloat16 h; short s; } u;
    u.h = __float2bfloat16(f);
    return u.s;
}
static __device__ __forceinline__ float getc(const float4& v, int k) {
    switch (k) { case 0: return v.x; case 1: return v.y; case 2: return v.z; default: return v.w; }
}

// Swizzled byte offset of a 16B column-octet slot in an 8KB [64][128B] plane.
static __device__ __forceinline__ int swz(int w, int row, int oct) {
    return w * 8192 + row * 128 + (((oct ^ row ^ w) & 7) << 4);
}

__global__ __launch_bounds__(1024, 8)
void polar_proj_kernel(const float* __restrict__ image,
                       const float* __restrict__ polar,
                       float* __restrict__ out_img,
                       float* __restrict__ out_cell) {
    __shared__ __align__(16) unsigned char sP[WT * 8192];  // polar bf16 [w][h][s] -> prob^T [w][z][h]
    __shared__ __align__(16) unsigned char sA[WT * 8192];  // image bf16 [w][d][h]

    const int t = threadIdx.x;

    // XCD-bijective swizzle: grid 1024 (%8==0).
    const int cpx = gridDim.x >> 3;
    const int logical = (blockIdx.x & 7) * cpx + (blockIdx.x >> 3);
    const int b  = logical >> 5;
    const int w0 = (logical & 31) << 2;

    // ---- 1. image loads: thread owns (d, h-quad) = 64B contiguous. ----
    const int d_im = t >> 4;
    const int h0   = (t & 15) << 2;
    float4 ir[4];
#pragma unroll
    for (int k = 0; k < 4; ++k)
        ir[k] = *(const float4*)(image + ((size_t)((b * D_ + d_im) * H_ + h0 + k)) * W_ + w0);

    // ---- 2. polar loads: 4 lanes x 64B contiguous per 256B row. ----
    const int q4  = t & 3;
    const int rr  = t >> 2;               // rr = w*64 + h, 0..255
    const int w_p = rr >> 6, h_p = rr & 63;
    const float* src = polar + ((size_t)((b * H_ + h_p) * W_ + w0 + w_p)) * S_ + q4 * 16;
    float4 pr[4];
#pragma unroll
    for (int k = 0; k < 4; ++k)
        pr[k] = *(const float4*)(src + k * 4);

    // ---- 3. image -> sA (bf16, b64 h-quad packs, swizzled). ----
#pragma unroll
    for (int w = 0; w < 4; ++w) {
        const short s0 = f2bf(getc(ir[0], w));
        const short s1 = f2bf(getc(ir[1], w));
        const short s2 = f2bf(getc(ir[2], w));
        const short s3 = f2bf(getc(ir[3], w));
        int2 pk;
        pk.x = (s0 & 0xffff) | (s1 << 16);
        pk.y = (s2 & 0xffff) | (s3 << 16);
        *(int2*)(sA + swz(w, d_im, h0 >> 3) + ((h0 & 7) << 1)) = pk;
    }

    // ---- 4. polar -> sP (bf16x8 b128, swizzled). ----
#pragma unroll
    for (int c = 0; c < 2; ++c) {
        bf16x8 v;
#pragma unroll
        for (int e = 0; e < 8; ++e)
            v[e] = f2bf(getc(pr[c * 2 + (e >> 2)], e & 3));
        *(bf16x8*)(sP + swz(w_p, h_p, q4 * 2 + c)) = v;
    }
    __syncthreads();   // staging ready

    // ---- 5. interp as MFMA with register-built Wz. wave = (wS, zq). ----
    const int lane = t & 63;
    const int wv   = t >> 6;              // 0..15
    const int fr   = lane & 15, lg = lane >> 4;
    const int wS   = wv >> 2, zq = wv & 3;

    const int z = zq * 16 + fr;
    const float posf = (log2f(0.5f + 0.5f * (float)z) + 1.0f) * 10.5f;  // (63/6)
    int i0 = (int)floorf(posf);
    i0 = i0 < 0 ? 0 : (i0 > S_ - 1 ? S_ - 1 : i0);
    const int i1 = (i0 + 1 > S_ - 1) ? (S_ - 1) : (i0 + 1);
    const float wz = posf - (float)i0;

    bf16x8 bw[2];   // Wz^T fragment: 2 nonzeros per z-column
#pragma unroll
    for (int ks = 0; ks < 2; ++ks)
#pragma unroll
        for (int e = 0; e < 8; ++e) {
            const int s = ks * 32 + lg * 8 + e;
            const float v = (s == i0 ? 1.0f - wz : 0.0f) + (s == i1 ? wz : 0.0f);
            bw[ks][e] = f2bf(v);
        }

    f32x4 sacc[4] = {};
#pragma unroll
    for (int ks = 0; ks < 2; ++ks)
#pragma unroll
        for (int mt = 0; mt < 4; ++mt) {
            const bf16x8 a = *(const bf16x8*)(sP + swz(wS, mt * 16 + fr, ks * 4 + lg));
            sacc[mt] = __builtin_amdgcn_mfma_f32_16x16x32_bf16(a, bw[ks], sacc[mt], 0, 0, 0);
        }

    // ---- softmax over h, in-register, no max-subtract (|score| <~ 6). ----
    float ex[4][4];
    float ss = 0.0f;
#pragma unroll
    for (int mt = 0; mt < 4; ++mt)
#pragma unroll
        for (int r = 0; r < 4; ++r) {
            const float e = __expf(sacc[mt][r]);
            ex[mt][r] = e;
            ss += e;
        }
    ss += __shfl_xor(ss, 16);
    ss += __shfl_xor(ss, 32);
    if (lg == 0)
        out_cell[((size_t)b * W_ + w0 + wS) * Z_ + z] = __logf(ss);
    const float inv = 1.0f / ss;
    __syncthreads();   // all S-GEMM reads of sP done; safe to overwrite

    // ---- 6. prob^T -> sP rows z (b64 packs of 4 h-contiguous bf16). ----
#pragma unroll
    for (int mt = 0; mt < 4; ++mt) {
        const short p0 = f2bf(ex[mt][0] * inv);
        const short p1 = f2bf(ex[mt][1] * inv);
        const short p2 = f2bf(ex[mt][2] * inv);
        const short p3 = f2bf(ex[mt][3] * inv);
        int2 pk;
        pk.x = (p0 & 0xffff) | (p1 << 16);
        pk.y = (p2 & 0xffff) | (p3 << 16);
        *(int2*)(sP + swz(wS, z, mt * 2 + (lg >> 1)) + ((lg & 1) << 3)) = pk;
    }
    __syncthreads();   // operands ready

    // ---- 7. PV GEMM: wave (mtp,ntp) does 16d x 16z x 4w, K=64. ----
    const int mtp = wv >> 2, ntp = wv & 3;
    f32x4 acc[4] = {};   // [w]
#pragma unroll
    for (int w = 0; w < 4; ++w)
#pragma unroll
        for (int ks = 0; ks < 2; ++ks) {
            const bf16x8 a  = *(const bf16x8*)(sA + swz(w, mtp * 16 + fr, ks * 4 + lg));
            const bf16x8 bb = *(const bf16x8*)(sP + swz(w, ntp * 16 + fr, ks * 4 + lg));
            acc[w] = __builtin_amdgcn_mfma_f32_16x16x32_bf16(a, bb, acc[w], 0, 0, 0);
        }

    // ---- 8. direct stores: one float4 over w per (d,z). ----
#pragma unroll
    for (int r = 0; r < 4; ++r) {
        const int d  = mtp * 16 + lg * 4 + r;
        const int zc = ntp * 16 + fr;
        float4 o;
        o.x = acc[0][r];
        o.y = acc[1][r];
        o.z = acc[2][r];
        o.w = acc[3][r];
        *(float4*)(out_img + ((size_t)((b * D_ + d) * Z_) + zc) * W_ + w0) = o;
    }
}

extern "C" void kernel_launch(void* const* d_in, const int* in_sizes, int n_in,
                              void* d_out, int out_size, void* d_ws, size_t ws_size,
                              hipStream_t stream) {
    const float* image = (const float*)d_in[0];
    const float* polar = (const float*)d_in[1];
    float* out_img  = (float*)d_out;
    float* out_cell = out_img + (size_t)B_ * D_ * Z_ * W_;
    dim3 grid(B_ * (W_ / WT));   // 1024 blocks
    polar_proj_kernel<<<grid, 1024, 0, stream>>>(image, polar, out_img, out_cell);
}